// Round 6
// baseline (387.753 us; speedup 1.0000x reference)
//
#include <hip/hip_runtime.h>

typedef short  bf16x8 __attribute__((ext_vector_type(8)));
typedef float  f32x4  __attribute__((ext_vector_type(4)));

__device__ __forceinline__ unsigned short f2bf(float x) {
    unsigned int u = __float_as_uint(x);
    u += 0x7FFFu + ((u >> 16) & 1u);   // round-to-nearest-even
    return (unsigned short)(u >> 16);
}
__device__ __forceinline__ unsigned int pack2(float lo, float hi) {
    return (unsigned int)f2bf(lo) | ((unsigned int)f2bf(hi) << 16);
}
__device__ __forceinline__ void gload_lds16(const void* g, void* l) {
    __builtin_amdgcn_global_load_lds(
        (const __attribute__((address_space(1))) void*)g,
        (__attribute__((address_space(3))) void*)l, 16, 0, 0);
}

// ---------------- bf16 MFMA GEMM body, 128x128 tile, K=256, BK=64 -------------
// A,B bf16. global_load_lds staging (16B/lane), double-buffered LDS, 4 K-steps
// (halved barrier/vmcnt-drain count vs BK=32 — drains were the measured stall).
// LDS [2][128][64] shorts per matrix = 64 KB total. Source-side XOR-unit
// swizzle (unit = 8 shorts): LDS[r][u] <- G[r][u ^ (r&7)]; read unit
// (kk*4+lq)^(l15&7) -> quarter-wave 2-way conflicts only (free).
template<bool OUT_BF16, int EPI>
__device__ __forceinline__
void gemm_body(const unsigned short* __restrict__ Ab,
               const unsigned short* __restrict__ Bt,
               const float* __restrict__ bias, void* __restrict__ Cout,
               int M, int lda, int ldc, int coff, int mBase, int nBase,
               unsigned short* SH)
{
    constexpr int BK = 64, NT = 4;      // K = 256
    const int tid = threadIdx.x;
    const int lane = tid & 63, wid = tid >> 6;
    const int wm = wid & 1, wn = wid >> 1;      // 2x2 waves, each 64x64
    const int l15 = lane & 15, lq = lane >> 4;
    const int swz = l15 & 7;                    // read-side unit swizzle

    unsigned short* As = SH;            // [2][128*64]
    unsigned short* Bs = SH + 16384;    // [2][128*64]

    const int sr = lane >> 3, su = lane & 7;    // staging row/unit within round
    const int gu = su ^ sr;                     // inverse-swizzled global unit

    f32x4 acc[4][4];
#pragma unroll
    for (int mt = 0; mt < 4; ++mt)
#pragma unroll
        for (int nt = 0; nt < 4; ++nt)
            acc[mt][nt] = (f32x4){0.f, 0.f, 0.f, 0.f};

    // stage K-step k0 into buffer b: 4 rounds x (A,B); wave covers 8 rows/round.
    // dest wave-uniform base + lane*16B lands at row (R+sr), unit su (linear).
    auto stage = [&](int b, int k0) {
#pragma unroll
        for (int s = 0; s < 4; ++s) {
            const int R = s * 32 + wid * 8;
            const int r = R + sr;
            gload_lds16(Ab + (size_t)(mBase + r) * lda + k0 + gu * 8,
                        &As[b * 8192 + R * 64]);
            gload_lds16(Bt + (size_t)(nBase + r) * 256 + k0 + gu * 8,
                        &Bs[b * 8192 + R * 64]);
        }
    };

    stage(0, 0);
    __syncthreads();
#pragma unroll
    for (int t = 0; t < NT; ++t) {
        const int b = t & 1;
        if (t < NT - 1) stage(b ^ 1, (t + 1) * BK);   // prefetch next K-step
#pragma unroll
        for (int kk = 0; kk < 2; ++kk) {
            bf16x8 af[4], bfr[4];
#pragma unroll
            for (int mt = 0; mt < 4; ++mt)
                af[mt] = *(const bf16x8*)&As[b * 8192 +
                            (wm * 64 + mt * 16 + l15) * 64 +
                            ((kk * 4 + lq) ^ swz) * 8];
#pragma unroll
            for (int nt = 0; nt < 4; ++nt)
                bfr[nt] = *(const bf16x8*)&Bs[b * 8192 +
                            (wn * 64 + nt * 16 + l15) * 64 +
                            ((kk * 4 + lq) ^ swz) * 8];
#pragma unroll
            for (int mt = 0; mt < 4; ++mt)
#pragma unroll
                for (int nt = 0; nt < 4; ++nt)
                    acc[mt][nt] = __builtin_amdgcn_mfma_f32_16x16x32_bf16(
                        af[mt], bfr[nt], acc[mt][nt], 0, 0, 0);
        }
        __syncthreads();
    }

#pragma unroll
    for (int mt = 0; mt < 4; ++mt) {
#pragma unroll
        for (int nt = 0; nt < 4; ++nt) {
            const int gn = nBase + wn * 64 + nt * 16 + l15;
#pragma unroll
            for (int i = 0; i < 4; ++i) {
                const int gm = mBase + wm * 64 + mt * 16 + lq * 4 + i;
                float v = acc[mt][nt][i];
                if (EPI == 2) v += bias[gn];
                if (EPI == 3) { if (gn < 256) v = fmaxf(v + bias[gn], 0.f); }
                if (OUT_BF16) {
                    ((unsigned short*)Cout)[(size_t)gm * ldc + coff + gn] = f2bf(v);
                } else {
                    if (gm < M)
                        ((float*)Cout)[(size_t)gm * ldc + coff + gn] = v;
                }
            }
        }
    }
}

// ---------------- D1: prep_all = weight conv + X->bf16 + histogram ------------
__global__ __launch_bounds__(256)
void prep_all(const float* __restrict__ mw1, const float* __restrict__ W1,
              const float* __restrict__ mw2, const float* __restrict__ W2,
              unsigned short* __restrict__ warena,
              const float* __restrict__ X, unsigned short* __restrict__ Xb,
              int N, int Mp,
              const int* __restrict__ dst, int* __restrict__ cnt, int E)
{
    const int bid = blockIdx.x;
    const int xBlocks = Mp / 8;
    if (bid < 768) {
        int i = bid * 256 + threadIdx.x;
        int r = i >> 8, k = i & 255;
        float v;
        if (r < 256)      v = mw1[k * 256 + r];
        else if (r < 512) v = W1[k * 256 + (r - 256)];
        else if (r < 640) v = mw2[k * 128 + (r - 512)];
        else              v = W2[k * 128 + (r - 640)];
        warena[i] = f2bf(v);
    } else if (bid < 768 + xBlocks) {
        int j = (bid - 768) * 256 + threadIdx.x;
        int row = j >> 5, seg = (j & 31) << 3;
        uint4 o;
        if (row < N) {
            const float4* p = (const float4*)&X[(size_t)row * 256 + seg];
            float4 f0 = p[0], f1 = p[1];
            o.x = pack2(f0.x, f0.y); o.y = pack2(f0.z, f0.w);
            o.z = pack2(f1.x, f1.y); o.w = pack2(f1.z, f1.w);
        } else {
            o = make_uint4(0u, 0u, 0u, 0u);
        }
        *(uint4*)&Xb[(size_t)row * 256 + seg] = o;
    } else {
        int e = (bid - 768 - xBlocks) * 256 + threadIdx.x;
        if (e < E) atomicAdd(&cnt[dst[e]], 1);
    }
}

// ---------------- D2: single-dispatch exclusive scan (ticket-master) ----------
__global__ __launch_bounds__(256)
void scan_one(const int* __restrict__ cnt, int* __restrict__ rowptr,
              int* __restrict__ pos, int n, int nb,
              int* __restrict__ agg, int* __restrict__ pref,
              int* __restrict__ ticket)
{
    __shared__ int s[256];
    __shared__ int m[256];
    __shared__ int ismaster, bcast;
    const int b = blockIdx.x, t = threadIdx.x;
    const int i = b * 256 + t;
    const int v = (i < n) ? cnt[i] : 0;
    s[t] = v;
    __syncthreads();
    for (int o = 1; o < 256; o <<= 1) {
        int u = (t >= o) ? s[t - o] : 0;
        __syncthreads();
        s[t] += u;
        __syncthreads();
    }
    const int incl = s[t];
    if (t == 0) {
        atomicExch(&agg[b], s[255]);
        __threadfence();
        int k = atomicAdd(ticket, 1);
        ismaster = (k == nb - 1);
    }
    __syncthreads();
    if (ismaster) {
        int a = (t < nb) ? atomicAdd(&agg[t], 0) : 0;
        m[t] = a;
        __syncthreads();
        for (int o = 1; o < 256; o <<= 1) {
            int u = (t >= o) ? m[t - o] : 0;
            __syncthreads();
            m[t] += u;
            __syncthreads();
        }
        if (t < nb) atomicExch(&pref[t], (m[t] - a) + 1);   // exclusive, +1 sentinel
        if (t == 0) rowptr[n] = m[nb - 1];
    }
    if (t == 0) {
        int p;
        do { p = atomicAdd(&pref[b], 0); } while (p == 0);
        bcast = p - 1;
    }
    __syncthreads();
    if (i < n) {
        int ex = bcast + incl - v;
        rowptr[i] = ex;
        pos[i] = ex;
    }
}

// ---------------- D3: fused gemmA + scatter (1:2) -----------------------------
__global__ __launch_bounds__(256)
void gemmA_scatter(const unsigned short* __restrict__ Xb,
                   const unsigned short* __restrict__ Wc,
                   const float* __restrict__ mb1, unsigned short* __restrict__ S1Y1,
                   int M, int G,
                   const int* __restrict__ src, const int* __restrict__ dst,
                   const float* __restrict__ w, int* __restrict__ pos,
                   int2* __restrict__ packed, int E)
{
    __shared__ __align__(16) unsigned short SH[32768];
    const int bid = blockIdx.x;
    const int r = bid % 3, g = bid / 3;
    if (bid < 3 * G && r == 0) {
        // sibling-adjacent decode: 4 column tiles of one row panel adjacent (L2)
        const int mBase = (g >> 2) * 128, nBase = (g & 3) * 128;
        gemm_body<true, 3>(Xb, Wc, mb1, S1Y1, M, 256, 512, 0, mBase, nBase, SH);
    } else {
        int sid = (bid < 3 * G) ? (2 * g + (r - 1)) : (2 * G + (bid - 3 * G));
        int e = sid * 256 + threadIdx.x;
        if (e >= E) return;
        int p = atomicAdd(&pos[dst[e]], 1);
        packed[p] = make_int2(src[e], __float_as_int(w[e]));
    }
}

// ---------------- D5: K2 and K4 in one dispatch -------------------------------
__global__ __launch_bounds__(256)
void k2k4(const unsigned short* __restrict__ S1Y1,
          const unsigned short* __restrict__ mw2t,
          const float* __restrict__ mb2, float* __restrict__ out,
          const unsigned short* __restrict__ h1b,
          const unsigned short* __restrict__ w2t,
          unsigned short* __restrict__ gb,
          int M, int ldc, int G)
{
    __shared__ __align__(16) unsigned short SH[32768];
    const int bid = blockIdx.x;
    if (bid < G) {
        // K2: out[:,0:128] = S1 @ mw2 + b2 (fp32)
        gemm_body<false, 2>(S1Y1, mw2t, mb2, out, M, 512, ldc, 0,
                            bid * 128, 0, SH);
    } else {
        // K4: gb = h1 @ W2 (bf16)
        gemm_body<true, 0>(h1b, w2t, nullptr, gb, M, 256, 128, 0,
                           (bid - G) * 128, 0, SH);
    }
}

// ---------------- gather SpMM over bf16 rows, 4-way edge unroll ---------------
template<int TPR, bool RELU, bool DUAL>
__global__ __launch_bounds__(256)
void spmm_csr_bf16(const unsigned short* __restrict__ x,
                   const int* __restrict__ rowptr, const int2* __restrict__ packed,
                   float* __restrict__ outf, unsigned short* __restrict__ outb,
                   int N, int ldx, int ldo, int coff, int ldd)
{
    const int rpb = 256 / TPR;
    const int r = blockIdx.x * rpb + threadIdx.x / TPR;
    const int lane = threadIdx.x % TPR;
    if (r >= N) return;
    const int beg = rowptr[r], end = rowptr[r + 1];
    const unsigned short* xp = x + lane * 8;
    float a0[8] = {0, 0, 0, 0, 0, 0, 0, 0};
    float a1[8] = {0, 0, 0, 0, 0, 0, 0, 0};
    int i = beg;
    for (; i + 3 < end; i += 4) {
        int2 e0 = packed[i], e1 = packed[i + 1], e2 = packed[i + 2], e3 = packed[i + 3];
        uint4 v0 = *(const uint4*)&xp[(size_t)e0.x * ldx];
        uint4 v1 = *(const uint4*)&xp[(size_t)e1.x * ldx];
        uint4 v2 = *(const uint4*)&xp[(size_t)e2.x * ldx];
        uint4 v3 = *(const uint4*)&xp[(size_t)e3.x * ldx];
        float w0 = __int_as_float(e0.y), w1 = __int_as_float(e1.y);
        float w2 = __int_as_float(e2.y), w3 = __int_as_float(e3.y);
        unsigned int s0[4] = {v0.x, v0.y, v0.z, v0.w};
        unsigned int s1[4] = {v1.x, v1.y, v1.z, v1.w};
        unsigned int s2[4] = {v2.x, v2.y, v2.z, v2.w};
        unsigned int s3[4] = {v3.x, v3.y, v3.z, v3.w};
#pragma unroll
        for (int j = 0; j < 4; ++j) {
            a0[2 * j]     = fmaf(w0, __uint_as_float(s0[j] << 16),         a0[2 * j]);
            a0[2 * j + 1] = fmaf(w0, __uint_as_float(s0[j] & 0xFFFF0000u), a0[2 * j + 1]);
            a1[2 * j]     = fmaf(w1, __uint_as_float(s1[j] << 16),         a1[2 * j]);
            a1[2 * j + 1] = fmaf(w1, __uint_as_float(s1[j] & 0xFFFF0000u), a1[2 * j + 1]);
            a0[2 * j]     = fmaf(w2, __uint_as_float(s2[j] << 16),         a0[2 * j]);
            a0[2 * j + 1] = fmaf(w2, __uint_as_float(s2[j] & 0xFFFF0000u), a0[2 * j + 1]);
            a1[2 * j]     = fmaf(w3, __uint_as_float(s3[j] << 16),         a1[2 * j]);
            a1[2 * j + 1] = fmaf(w3, __uint_as_float(s3[j] & 0xFFFF0000u), a1[2 * j + 1]);
        }
    }
    for (; i + 1 < end; i += 2) {
        int2 e0 = packed[i], e1 = packed[i + 1];
        uint4 v0 = *(const uint4*)&xp[(size_t)e0.x * ldx];
        uint4 v1 = *(const uint4*)&xp[(size_t)e1.x * ldx];
        float w0 = __int_as_float(e0.y), w1 = __int_as_float(e1.y);
        unsigned int s0[4] = {v0.x, v0.y, v0.z, v0.w};
        unsigned int s1[4] = {v1.x, v1.y, v1.z, v1.w};
#pragma unroll
        for (int j = 0; j < 4; ++j) {
            a0[2 * j]     = fmaf(w0, __uint_as_float(s0[j] << 16),         a0[2 * j]);
            a0[2 * j + 1] = fmaf(w0, __uint_as_float(s0[j] & 0xFFFF0000u), a0[2 * j + 1]);
            a1[2 * j]     = fmaf(w1, __uint_as_float(s1[j] << 16),         a1[2 * j]);
            a1[2 * j + 1] = fmaf(w1, __uint_as_float(s1[j] & 0xFFFF0000u), a1[2 * j + 1]);
        }
    }
    if (i < end) {
        int2 e0 = packed[i];
        uint4 v0 = *(const uint4*)&xp[(size_t)e0.x * ldx];
        float w0 = __int_as_float(e0.y);
        unsigned int s0[4] = {v0.x, v0.y, v0.z, v0.w};
#pragma unroll
        for (int j = 0; j < 4; ++j) {
            a0[2 * j]     = fmaf(w0, __uint_as_float(s0[j] << 16),         a0[2 * j]);
            a0[2 * j + 1] = fmaf(w0, __uint_as_float(s0[j] & 0xFFFF0000u), a0[2 * j + 1]);
        }
    }
    float acc[8];
#pragma unroll
    for (int j = 0; j < 8; ++j) {
        acc[j] = a0[j] + a1[j];
        if (RELU) acc[j] = fmaxf(acc[j], 0.f);
    }
    float* o = &outf[(size_t)r * ldo + coff + lane * 8];
    *(float4*)o       = make_float4(acc[0], acc[1], acc[2], acc[3]);
    *(float4*)(o + 4) = make_float4(acc[4], acc[5], acc[6], acc[7]);
    if (DUAL) {
        uint4 p;
        p.x = pack2(acc[0], acc[1]); p.y = pack2(acc[2], acc[3]);
        p.z = pack2(acc[4], acc[5]); p.w = pack2(acc[6], acc[7]);
        *(uint4*)&outb[(size_t)r * ldd + lane * 8] = p;
    }
}

// ---------------- launch ------------------------------------------------------
extern "C" void kernel_launch(void* const* d_in, const int* in_sizes, int n_in,
                              void* d_out, int out_size, void* d_ws, size_t ws_size,
                              hipStream_t stream)
{
    const float* X    = (const float*)d_in[0];
    const int*   esrc = (const int*)  d_in[1];
    const int*   edst = (const int*)  d_in[2];
    const float* ew   = (const float*)d_in[3];
    const float* W1   = (const float*)d_in[4];
    const float* W2   = (const float*)d_in[5];
    const float* mw1  = (const float*)d_in[6];
    const float* mb1  = (const float*)d_in[7];
    const float* mw2  = (const float*)d_in[8];
    const float* mb2  = (const float*)d_in[9];

    const int IN_F = 256, HID_F = 256, OUT_F = 128;
    const int N  = in_sizes[0] / IN_F;
    const int E  = in_sizes[1];
    const int LD = OUT_F + HID_F + OUT_F;       // 512
    const int Mp = (N + 127) & ~127;

    float* out = (float*)d_out;

    // workspace (shorts)
    unsigned short* S1Y1  = (unsigned short*)d_ws;          // [Mp][512]: S1 | Y1
    unsigned short* Xb    = S1Y1 + (size_t)Mp * 512;        // [Mp][256] X bf16
    unsigned short* h1b   = Xb;                             // h1 bf16 reuses Xb (dead after gemmA)
    unsigned short* gb    = Xb   + (size_t)Mp * 256;        // [Mp][128]
    unsigned short* warena = gb  + (size_t)Mp * 128;        // [768][256]
    unsigned short* Wc   = warena;                          // [512][256]
    unsigned short* mw2t = warena + 512 * 256;              // [128][256]
    unsigned short* w2t  = warena + 640 * 256;              // [128][256]

    // int region (zeroed by one memset node): rowptr | agg | pref | ticket
    int* iw     = (int*)(warena + 768 * 256);
    int* rowptr = iw;                                       // N+1
    const int aggOff = ((N + 1) + 3) & ~3;
    int* agg    = iw + aggOff;                              // 256
    int* pref   = agg + 256;                                // 256
    int* ticket = pref + 256;                               // 4 (1 used)
    int* pos    = ticket + 4;                               // N
    int2* packed = (int2*)(pos + ((N + 1) & ~1));           // E

    dim3 blk(256);
    const int nb = (N + 255) / 256;         // 196 (<=256 required by scan_one)
    const int mT = Mp / 128;                // 391
    const int He = (E + 255) / 256;         // hist/scatter block count

    // D0: zero rowptr + agg + pref + ticket in one memset node
    hipMemsetAsync(iw, 0, (size_t)(aggOff + 516) * sizeof(int), stream);

    // D1: weights conv + X fp32->bf16 + degree histogram
    prep_all<<<768 + Mp / 8 + He, blk, 0, stream>>>(
        mw1, W1, mw2, W2, warena, X, Xb, N, Mp, edst, rowptr, E);

    // D2: exclusive scan -> rowptr, pos (single dispatch)
    scan_one<<<nb, blk, 0, stream>>>(rowptr, rowptr, pos, N, nb, agg, pref, ticket);

    // D3: fused gemmA + scatter
    {
        const int G = mT * 4;
        int grid = 3 * G + ((He > 2 * G) ? (He - 2 * G) : 0);
        gemmA_scatter<<<grid, blk, 0, stream>>>(
            Xb, Wc, mb1, S1Y1, N, G, esrc, edst, ew, pos, packed, E);
    }

    // D4: SpMM1: h1 = relu(A @ Y1) -> out[:,128:384] fp32 + h1b bf16
    spmm_csr_bf16<32, true, true><<<(N + 7) / 8, blk, 0, stream>>>(
        S1Y1 + 256, rowptr, packed, out, h1b, N, 512, LD, OUT_F, 256);

    // D5: K2 (out[:,0:128] = S1@mw2+b2) and K4 (gb = h1@W2) in one dispatch
    k2k4<<<2 * mT, blk, 0, stream>>>(
        S1Y1, mw2t, mb2, out, h1b, w2t, gb, N, LD, mT);

    // D6: SpMM2: out[:,384:512] = A @ g (fp32)
    spmm_csr_bf16<16, false, false><<<(N + 15) / 16, blk, 0, stream>>>(
        gb, rowptr, packed, out, nullptr, N, 128, LD, OUT_F + HID_F, 0);
}